// Round 10
// baseline (245.223 us; speedup 1.0000x reference)
//
#include <hip/hip_runtime.h>
#include <hip/hip_bf16.h>

typedef __attribute__((ext_vector_type(8))) short short8;
typedef __attribute__((ext_vector_type(4))) float floatx4;
typedef __hip_bfloat16 bf16;

#define DIM 768
#define NH 12
#define HD 64
#define BB 16
#define NN 640
#define BH (BB*NH)          // 192
#define MROWS (BB*NN)       // 10240
#define QKVN (3*DIM)        // 2304
#define QSCALE 0.18033688011113205f   // 0.125 * log2(e)
#define LN2SQ 0.4804530139182014f     // ln(2)^2

#define CVT_BLK (MROWS*DIM/4/256)     // 7680
#define TRQ_BLK ((QKVN/32)*(DIM/32))  // 1728
#define TRP_BLK ((DIM/32)*(DIM/32))   // 576

__device__ __forceinline__ floatx4 mfma16(short8 a, short8 b, floatx4 c) {
    return __builtin_amdgcn_mfma_f32_16x16x32_bf16(a, b, c, 0, 0, 0);
}

// async global->LDS, 16B per lane; lds dest = wave-uniform base + lane*16
__device__ __forceinline__ void async_ld16(const bf16* g, bf16* l) {
    __builtin_amdgcn_global_load_lds(
        (const __attribute__((address_space(1))) void*)g,
        (__attribute__((address_space(3))) void*)l, 16, 0, 0);
}

// truncate two f32 to bf16 and pack: lo16 = a, hi16 = b  (one v_perm_b32)
__device__ __forceinline__ unsigned pack_trunc(float a, float b) {
    return __builtin_amdgcn_perm(__float_as_uint(b), __float_as_uint(a), 0x07060302u);
}

// RNE two f32 -> packed bf16x2 (matches __float2bfloat16 numerics)
__device__ __forceinline__ unsigned pack_rne(float a, float b) {
    unsigned sa = (unsigned)__bfloat16_as_ushort(__float2bfloat16(a));
    unsigned sb = (unsigned)__bfloat16_as_ushort(__float2bfloat16(b));
    return sa | (sb << 16);
}

__device__ __forceinline__ float fexp2(float x) {
#if __has_builtin(__builtin_amdgcn_exp2f)
    return __builtin_amdgcn_exp2f(x);
#else
    return exp2f(x);
#endif
}

// ---------------- fused prep: x->bf16 + both weight transposes ----------------
// (round-8 exact)
__global__ void prep_all(const float* __restrict__ x,
                         const float* __restrict__ qkv_w,
                         const float* __restrict__ proj_w,
                         bf16* __restrict__ xb,
                         bf16* __restrict__ qwT,
                         bf16* __restrict__ pwT)
{
    __shared__ float tile[32][33];
    const int id = blockIdx.x;
    const int t = threadIdx.x;

    if (id < CVT_BLK) {
        int i = id * 256 + t;
        float4 v = ((const float4*)x)[i];
        *(uint2*)(xb + (size_t)i * 4) =
            make_uint2(pack_rne(v.x, v.y), pack_rne(v.z, v.w));
        return;
    }

    const float* src; bf16* dst; int C, bx, by;
    if (id < CVT_BLK + TRQ_BLK) {
        int j = id - CVT_BLK;
        bx = j % (QKVN/32); by = j / (QKVN/32);
        src = qkv_w; dst = qwT; C = QKVN;
    } else {
        int j = id - CVT_BLK - TRQ_BLK;
        bx = j % (DIM/32); by = j / (DIM/32);
        src = proj_w; dst = pwT; C = DIM;
    }
    const int R = DIM;
    const int tx = t & 31, ty = t >> 5;
    for (int j = 0; j < 4; ++j)
        tile[ty + j*8][tx] = src[(size_t)(by*32 + ty + j*8) * C + bx*32 + tx];
    __syncthreads();
    for (int j = 0; j < 4; ++j)
        dst[(size_t)(bx*32 + ty + j*8) * R + by*32 + tx] = __float2bfloat16(tile[tx][ty + j*8]);
}

// ---------------- QKV GEMM: 128x192 tile, 2-barrier loop, 2 blocks/CU ----------------
// C = A @ B^T, A [10240][768], B [2304][768] bf16. 256 thr / 4 waves (2M x 2N),
// per-wave 64x96 (acc[4][6]). BK=64 double-buffered; LDS 80 KiB EXACTLY ->
// 2 blocks/CU (cross-block overlap fills barrier drains — the r0-structure
// property the 1-block/CU 6-phase lacked). Grid 960 = 1.875 rounds of the
// 512-block capacity. ds_read:MFMA = 20:48 per K-tile (was 16:32 at 128^2).
// Staging/swizzle laws identical to the verified r0/r6 kernels; epilogues
// transplanted from the twice-verified 256x192 6-phase kernel.
__global__ __launch_bounds__(256) void gemm_qkv(
    const bf16* __restrict__ A, const bf16* __restrict__ B, const float* __restrict__ bias,
    bf16* __restrict__ outb, bf16* __restrict__ vTo)
{
    constexpr int K = DIM;                   // 768: 12 K-tiles
    constexpr int N = QKVN;                  // 2304
    constexpr int GX = N / 192;              // 12
    constexpr int NWG = GX * (MROWS / 128);  // 960
    constexpr int CHUNK = NWG / 8;           // 120 (960 % 8 == 0)

    __shared__ __align__(16) bf16 As[2][128*64];   // 32 KiB
    __shared__ __align__(16) bf16 Bs[2][192*64];   // 48 KiB

    const int t = threadIdx.x;
    const int lane = t & 63, wave = t >> 6;
    const int l15 = lane & 15, quad = lane >> 4;
    const int wm = (wave >> 1) * 64;         // 0 / 64
    const int wn = (wave & 1) * 96;          // 0 / 96

    int lin = blockIdx.x;
    lin = (lin & 7) * CHUNK + (lin >> 3);    // XCD-chunked bijection
    const int m0 = (lin / GX) * 128, n0 = (lin % GX) * 192;

    floatx4 acc[4][6];
    floatx4 zero = {0.f, 0.f, 0.f, 0.f};
#pragma unroll
    for (int i = 0; i < 4; ++i)
#pragma unroll
        for (int j = 0; j < 6; ++j)
            acc[i][j] = zero;

    // staging: call s covers rows s*32 + (t>>3); slot t&7; chunk = slot^(row&7)
    const int trow = t >> 3;
    const int gc = ((t & 7) ^ (trow & 7)) << 3;
    const bf16* aA = A + (size_t)(m0 + trow) * K + gc;
    const bf16* aB = B + (size_t)(n0 + trow) * K + gc;
    const int lb = wave * 512;               // wave-uniform LDS elem base per call

    // prologue: tile 0 into buf 0 (A 4 calls, B 6 calls)
#pragma unroll
    for (int s = 0; s < 4; ++s)
        async_ld16(aA + (size_t)s*32*K, &As[0][s*2048 + lb]);
#pragma unroll
    for (int s = 0; s < 6; ++s)
        async_ld16(aB + (size_t)s*32*K, &Bs[0][s*2048 + lb]);

    const int sw = l15 & 7;
    const int nit = K >> 6;                  // 12 (even -> buf0 idle at exit)
    for (int kt = 0; kt < nit; ++kt) {
        const int cur = kt & 1;
        __syncthreads();   // drains prefetch into buf cur; protects buf cur^1 overwrite
        if (kt + 1 < nit) {
            const bf16* pA = aA + (size_t)(kt+1)*64;
            const bf16* pB = aB + (size_t)(kt+1)*64;
#pragma unroll
            for (int s = 0; s < 4; ++s)
                async_ld16(pA + (size_t)s*32*K, &As[cur^1][s*2048 + lb]);
#pragma unroll
            for (int s = 0; s < 6; ++s)
                async_ld16(pB + (size_t)s*32*K, &Bs[cur^1][s*2048 + lb]);
        }
        short8 af0[4], af1[4], bf0[6], bf1[6];
#pragma unroll
        for (int fm = 0; fm < 4; ++fm) {
            int base = (wm + fm*16 + l15) * 64 + ((quad ^ sw) << 3);
            af0[fm] = *(const short8*)(&As[cur][base]);
            af1[fm] = *(const short8*)(&As[cur][base ^ 32]);
        }
#pragma unroll
        for (int fn = 0; fn < 6; ++fn) {
            int base = (wn + fn*16 + l15) * 64 + ((quad ^ sw) << 3);
            bf0[fn] = *(const short8*)(&Bs[cur][base]);
            bf1[fn] = *(const short8*)(&Bs[cur][base ^ 32]);
        }
#pragma unroll
        for (int fm = 0; fm < 4; ++fm)
#pragma unroll
            for (int fn = 0; fn < 6; ++fn) {
                acc[fm][fn] = mfma16(bf0[fn], af0[fm], acc[fm][fn]);
                acc[fm][fn] = mfma16(bf1[fn], af1[fm], acc[fm][fn]);
            }
    }

    // ---- epilogue: acc[fm][fn][r] = C[m0+wm+fm*16+l15][n0+wn+fn*16+quad*4+r]
    const int mb = m0 + wm;
    const int nb = n0 + wn;

    if (n0 >= 2*DIM) {
        // V tiles (n0 in {1536,1728,1920,2112}): per fn, 16-col block within one
        // head (16|64); 64-row wave span within one batch (64|640). Per-wave LDS
        // transpose scratch in As[0] (idle since last barrier, nit even; other
        // waves read only As[1]/Bs[1] in their final compute; 4 waves x 2048 =
        // 8192 = As[0] size). Then coalesced uint4 stores to vT[bh][d][tok].
        bf16* S = &As[0][0] + wave * 2048;
        unsigned short* Su = (unsigned short*)S;
        const int batch = mb / NN;
        const int tokb = mb % NN;
        const int dl = lane >> 2, cc = (lane & 3) * 16;
#pragma unroll
        for (int fn = 0; fn < 6; ++fn) {
            int cb = nb + fn*16;
            int bh = batch * NH + ((cb - 2*DIM) >> 6);
            int dbase = cb & 63;
            float4 bv = *(const float4*)(bias + cb + quad*4);
            float bvr[4] = {bv.x, bv.y, bv.z, bv.w};
#pragma unroll
            for (int fm = 0; fm < 4; ++fm) {
#pragma unroll
                for (int r = 0; r < 4; ++r) {
                    float v = acc[fm][fn][r] + bvr[r];
                    Su[(quad*4 + r)*72 + fm*16 + l15] =
                        (unsigned short)(__float_as_uint(v) >> 16);
                }
            }
            // per-wave scratch: in-wave lgkmcnt ordering suffices
            uint4 r0 = *(const uint4*)(S + dl*72 + cc);
            uint4 r1 = *(const uint4*)(S + dl*72 + cc + 8);
            bf16* dst = vTo + ((size_t)bh * HD + dbase + dl) * NN + tokb + cc;
            *(uint4*)dst = r0;
            *(uint4*)(dst + 8) = r1;
        }
        return;
    }

#pragma unroll
    for (int fm = 0; fm < 4; ++fm) {
        int m = mb + fm*16 + l15;
        bf16* row = outb + (size_t)m * N;
#pragma unroll
        for (int fn = 0; fn < 6; ++fn) {
            int n = nb + fn*16 + quad*4;
            float4 bv = *(const float4*)(bias + n);
            float v0 = acc[fm][fn][0] + bv.x;
            float v1 = acc[fm][fn][1] + bv.y;
            float v2 = acc[fm][fn][2] + bv.z;
            float v3 = acc[fm][fn][3] + bv.w;
            if (n < DIM) { v0 *= QSCALE; v1 *= QSCALE; v2 *= QSCALE; v3 *= QSCALE; }
            *(uint2*)(row + n) = make_uint2(pack_rne(v0, v1), pack_rne(v2, v3));
        }
    }
}

// ---------------- proj GEMM: C = A @ B^T (128x128, round-8 exact) ----------------
template<int MODE>
__global__ __launch_bounds__(256) void gemm_bt(
    const bf16* __restrict__ A, const bf16* __restrict__ B, const float* __restrict__ bias,
    int M, int N, int K,
    bf16* __restrict__ outb, bf16* __restrict__ vTo, float* __restrict__ outf)
{
    __shared__ __align__(16) bf16 As[2][128*64];
    __shared__ __align__(16) bf16 Bs[2][128*64];

    const int t = threadIdx.x;
    const int lane = t & 63, wave = t >> 6;
    const int l15 = lane & 15, quad = lane >> 4;
    const int wm = (wave >> 1) * 64, wn = (wave & 1) * 64;

    constexpr int GX  = (MODE == 0) ? (QKVN/128) : (DIM/128);
    constexpr int NWG = GX * (MROWS/128);
    constexpr int CHUNK = NWG / 8;
    int lin = blockIdx.y * GX + blockIdx.x;
    lin = (lin & 7) * CHUNK + (lin >> 3);
    const int m0 = (lin / GX) * 128, n0 = (lin % GX) * 128;

    floatx4 acc[4][4];
    floatx4 zero = {0.f, 0.f, 0.f, 0.f};
    for (int i = 0; i < 4; ++i)
        for (int j = 0; j < 4; ++j)
            acc[i][j] = zero;

    const int trow = t >> 3;
    const int gc = ((t & 7) ^ (trow & 7)) << 3;
    const bf16* aA = A + (size_t)(m0 + trow) * K + gc;
    const bf16* aB = B + (size_t)(n0 + trow) * K + gc;
    const int lb = wave * 512;

    for (int s = 0; s < 4; ++s) {
        async_ld16(aA + (size_t)s*32*K, &As[0][s*2048 + lb]);
        async_ld16(aB + (size_t)s*32*K, &Bs[0][s*2048 + lb]);
    }

    const int sw = l15 & 7;
    const int nit = K >> 6;
    for (int kt = 0; kt < nit; ++kt) {
        const int cur = kt & 1;
        __syncthreads();
        if (kt + 1 < nit) {
            const bf16* pA = aA + (size_t)(kt+1)*64;
            const bf16* pB = aB + (size_t)(kt+1)*64;
            for (int s = 0; s < 4; ++s) {
                async_ld16(pA + (size_t)s*32*K, &As[cur^1][s*2048 + lb]);
                async_ld16(pB + (size_t)s*32*K, &Bs[cur^1][s*2048 + lb]);
            }
        }
        short8 af0[4], af1[4], bf0[4], bf1[4];
        for (int fm = 0; fm < 4; ++fm) {
            int base = (wm + fm*16 + l15) * 64 + ((quad ^ sw) << 3);
            af0[fm] = *(const short8*)(&As[cur][base]);
            af1[fm] = *(const short8*)(&As[cur][base ^ 32]);
        }
        for (int fn = 0; fn < 4; ++fn) {
            int base = (wn + fn*16 + l15) * 64 + ((quad ^ sw) << 3);
            bf0[fn] = *(const short8*)(&Bs[cur][base]);
            bf1[fn] = *(const short8*)(&Bs[cur][base ^ 32]);
        }
        for (int fm = 0; fm < 4; ++fm)
            for (int fn = 0; fn < 4; ++fn) {
                acc[fm][fn] = mfma16(bf0[fn], af0[fm], acc[fm][fn]);
                acc[fm][fn] = mfma16(bf1[fn], af1[fm], acc[fm][fn]);
            }
    }

    for (int fm = 0; fm < 4; ++fm) {
        int m = m0 + wm + fm*16 + l15;
        float* row = outf + (size_t)m * N;
        for (int fn = 0; fn < 4; ++fn) {
            int n = n0 + wn + fn*16 + quad*4;
            float4 bv = *(const float4*)(bias + n);
            float4 v;
            v.x = acc[fm][fn][0] + bv.x;
            v.y = acc[fm][fn][1] + bv.y;
            v.z = acc[fm][fn][2] + bv.z;
            v.w = acc[fm][fn][3] + bv.w;
            *(float4*)(row + n) = v;
        }
    }
}

// ---------------- fused attention v9: v7 body, 8-wave blocks (round-8 exact) ----------------
__global__ __launch_bounds__(512) void attn_kernel(
    const bf16* __restrict__ qkv, const bf16* __restrict__ vT,
    const float* __restrict__ w2, bf16* __restrict__ ao)
{
    int lin = blockIdx.y * BH + blockIdx.x;     // grid (192, 5)
    int j = lin >> 3;
    const int bh = (lin & 7) + 8 * (j / 5);     // bijective: 8 * 24 * 5 = 960
    const int qt = j % 5;
    const int b = bh / NH, h = bh - b * NH;
    const int t = threadIdx.x;
    const int wave = t >> 6, lane = t & 63;
    const int l15 = lane & 15, quad = lane >> 4;
    const int qrow0 = qt * 128 + wave * 16;

    float w0 = w2[0], w1 = w2[1];
    float wmx = fmaxf(w0, w1);
    float e0 = __expf(w0 - wmx), e1 = __expf(w1 - wmx);
    float ws0 = e0 / (e0 + e1);
    float ws1 = (1.0f - ws0) * LN2SQ;

    __shared__ __align__(16) bf16 Kb[2][64*64];
    __shared__ __align__(16) bf16 Vb[2][64*64];
    __shared__ __align__(16) bf16 Ps[8][16*72];
    __shared__ __align__(16) bf16 Pr[8][16*72];

    const bf16* kb = qkv + (size_t)(b*NN)*QKVN + DIM + h*HD;
    const bf16* vb = vT + (size_t)bh * HD * NN;

    const bf16* qr = qkv + (size_t)(b*NN + qrow0 + l15) * QKVN + h*HD;
    short8 aq0 = *(const short8*)(qr + quad*8);
    short8 aq1 = *(const short8*)(qr + 32 + quad*8);

    const int srow = t >> 3;
    const int gc   = ((t & 7) ^ (srow & 7)) << 3;
    const bf16* kst = kb + (size_t)srow * QKVN + gc;
    const bf16* vst = vb + (size_t)srow * NN + gc;
    const int lb = t * 8;

    async_ld16(kst, &Kb[0][lb]);
    async_ld16(vst, &Vb[0][lb]);

    floatx4 zero = {0.f, 0.f, 0.f, 0.f};
    floatx4 accS[4], accR[4];
    for (int i = 0; i < 4; ++i) { accS[i] = zero; accR[i] = zero; }
    float lsum = 0.f;

    const int sw = l15 & 7;
    const int fbase = l15 * 64 + ((quad ^ sw) << 3);

    unsigned* PsW = (unsigned*)&Ps[wave][0];
    unsigned* PrW = (unsigned*)&Pr[wave][0];
    const int wb = l15*36 + quad*2;
    const bf16* PsR = &Ps[wave][l15*72 + quad*8];
    const bf16* PrR = &Pr[wave][l15*72 + quad*8];

#pragma unroll 2
    for (int kt = 0; kt < 10; ++kt) {
        const int cur = kt & 1;
        __syncthreads();
        if (kt + 1 < 10) {
            kst += (size_t)64 * QKVN;
            vst += 64;
            async_ld16(kst, &Kb[cur^1][lb]);
            async_ld16(vst, &Vb[cur^1][lb]);
        }

        const bf16* Kc = &Kb[cur][0];
        const bf16* Vc = &Vb[cur][0];

        floatx4 s[4];
        for (int I = 0; I < 4; ++I) {
            short8 aklo = *(const short8*)(Kc + fbase + I*1024);
            short8 akhi = *(const short8*)(Kc + ((fbase + I*1024) ^ 32));
            s[I] = zero;
            s[I] = mfma16(aklo, aq0, s[I]);
            s[I] = mfma16(akhi, aq1, s[I]);
        }

        short8 bvlo[4], bvhi[4];
        for (int dt = 0; dt < 4; ++dt) {
            bvlo[dt] = *(const short8*)(Vc + fbase + dt*1024);
            bvhi[dt] = *(const short8*)(Vc + ((fbase + dt*1024) ^ 32));
        }

        for (int I = 0; I < 4; ++I) {
            float ex[4], rq[4];
            for (int r = 0; r < 4; ++r) {
                ex[r] = fexp2(s[I][r]);
                float m = fmaxf(s[I][r], 0.f);
                rq[r] = m * m;
                lsum += ex[r];
            }
            *(uint2*)(PsW + wb + I*8) = make_uint2(pack_trunc(ex[0],ex[1]), pack_trunc(ex[2],ex[3]));
            *(uint2*)(PrW + wb + I*8) = make_uint2(pack_trunc(rq[0],rq[1]), pack_trunc(rq[2],rq[3]));
        }

        short8 paSlo = *(const short8*)PsR;
        short8 paShi = *(const short8*)(PsR + 32);
        short8 paRlo = *(const short8*)PrR;
        short8 paRhi = *(const short8*)(PrR + 32);

        for (int dt = 0; dt < 4; ++dt) {
            accS[dt] = mfma16(paSlo, bvlo[dt], accS[dt]);
            accS[dt] = mfma16(paShi, bvhi[dt], accS[dt]);
            accR[dt] = mfma16(paRlo, bvlo[dt], accR[dt]);
            accR[dt] = mfma16(paRhi, bvhi[dt], accR[dt]);
        }
    }

    lsum += __shfl_xor(lsum, 16);
    lsum += __shfl_xor(lsum, 32);
    float invq[4];
    for (int r = 0; r < 4; ++r)
        invq[r] = 1.0f / __shfl(lsum, quad*4 + r);

    for (int dt = 0; dt < 4; ++dt) {
        for (int r = 0; r < 4; ++r) {
            float v = ws0 * accS[dt][r] * invq[r] + ws1 * accR[dt][r];
            int tok = qrow0 + quad*4 + r;
            ao[((size_t)(b * NN + tok)) * DIM + h * HD + dt*16 + l15] = __float2bfloat16(v);
        }
    }
}

// ---------------- launch ----------------

extern "C" void kernel_launch(void* const* d_in, const int* in_sizes, int n_in,
                              void* d_out, int out_size, void* d_ws, size_t ws_size,
                              hipStream_t stream) {
    const float* x      = (const float*)d_in[0];
    const float* qkv_w  = (const float*)d_in[1];
    const float* qkv_b  = (const float*)d_in[2];
    const float* proj_w = (const float*)d_in[3];
    const float* proj_b = (const float*)d_in[4];
    const float* w2     = (const float*)d_in[5];
    float* out = (float*)d_out;

    bf16* xb   = (bf16*)d_ws;                       // 10240*768   (reused as ao later)
    bf16* qwT  = xb   + (size_t)MROWS * DIM;        // 2304*768
    bf16* pwT  = qwT  + (size_t)QKVN * DIM;         // 768*768
    bf16* qkvb = pwT  + (size_t)DIM * DIM;          // 10240*2304 (V cols unused)
    bf16* vT   = qkvb + (size_t)MROWS * QKVN;       // 192*64*640
    bf16* ao   = xb;                                 // alias: xb dead after qkv gemm

    prep_all<<<CVT_BLK + TRQ_BLK + TRP_BLK, 256, 0, stream>>>(
        x, qkv_w, proj_w, xb, qwT, pwT);

    gemm_qkv<<<dim3((QKVN/192) * (MROWS/128)), 256, 0, stream>>>(
        xb, qwT, qkv_b, qkvb, vT);

    attn_kernel<<<dim3(BH, NN / 128), 512, 0, stream>>>(qkvb, vT, w2, ao);

    gemm_bt<1><<<dim3(DIM / 128, MROWS / 128), 256, 0, stream>>>(
        ao, pwT, proj_b, MROWS, DIM, DIM, nullptr, nullptr, out);
}

// Round 11
// 209.315 us; speedup vs baseline: 1.1716x; 1.1716x over previous
//
#include <hip/hip_runtime.h>
#include <hip/hip_bf16.h>

typedef __attribute__((ext_vector_type(8))) short short8;
typedef __attribute__((ext_vector_type(4))) float floatx4;
typedef __hip_bfloat16 bf16;

#define DIM 768
#define NH 12
#define HD 64
#define BB 16
#define NN 640
#define BH (BB*NH)          // 192
#define MROWS (BB*NN)       // 10240
#define QKVN (3*DIM)        // 2304
#define QSCALE 0.18033688011113205f   // 0.125 * log2(e)
#define LN2SQ 0.4804530139182014f     // ln(2)^2

#define CVT_BLK (MROWS*DIM/8/256)     // 3840 (2 float4 per thread)
#define TRQ_BLK ((QKVN/32)*(DIM/32))  // 1728
#define TRP_BLK ((DIM/32)*(DIM/32))   // 576

__device__ __forceinline__ floatx4 mfma16(short8 a, short8 b, floatx4 c) {
    return __builtin_amdgcn_mfma_f32_16x16x32_bf16(a, b, c, 0, 0, 0);
}

// async global->LDS, 16B per lane; lds dest = wave-uniform base + lane*16
__device__ __forceinline__ void async_ld16(const bf16* g, bf16* l) {
    __builtin_amdgcn_global_load_lds(
        (const __attribute__((address_space(1))) void*)g,
        (__attribute__((address_space(3))) void*)l, 16, 0, 0);
}

// truncate two f32 to bf16 and pack: lo16 = a, hi16 = b  (one v_perm_b32)
__device__ __forceinline__ unsigned pack_trunc(float a, float b) {
    return __builtin_amdgcn_perm(__float_as_uint(b), __float_as_uint(a), 0x07060302u);
}

// RNE two f32 -> packed bf16x2 (matches __float2bfloat16 numerics)
__device__ __forceinline__ unsigned pack_rne(float a, float b) {
    unsigned sa = (unsigned)__bfloat16_as_ushort(__float2bfloat16(a));
    unsigned sb = (unsigned)__bfloat16_as_ushort(__float2bfloat16(b));
    return sa | (sb << 16);
}

__device__ __forceinline__ float fexp2(float x) {
#if __has_builtin(__builtin_amdgcn_exp2f)
    return __builtin_amdgcn_exp2f(x);
#else
    return exp2f(x);
#endif
}

// ---------------- fused prep: x->bf16 + both weight transposes ----------------
__global__ void prep_all(const float* __restrict__ x,
                         const float* __restrict__ qkv_w,
                         const float* __restrict__ proj_w,
                         bf16* __restrict__ xb,
                         bf16* __restrict__ qwT,
                         bf16* __restrict__ pwT)
{
    __shared__ float tile[32][33];
    const int id = blockIdx.x;
    const int t = threadIdx.x;

    if (id < CVT_BLK) {
        // two coalesced float4s per thread
        int i0 = id * 512 + t;
        float4 v0 = ((const float4*)x)[i0];
        float4 v1 = ((const float4*)x)[i0 + 256];
        *(uint2*)(xb + (size_t)i0 * 4) =
            make_uint2(pack_rne(v0.x, v0.y), pack_rne(v0.z, v0.w));
        *(uint2*)(xb + (size_t)(i0 + 256) * 4) =
            make_uint2(pack_rne(v1.x, v1.y), pack_rne(v1.z, v1.w));
        return;
    }

    const float* src; bf16* dst; int C, bx, by;
    if (id < CVT_BLK + TRQ_BLK) {
        int j = id - CVT_BLK;
        bx = j % (QKVN/32); by = j / (QKVN/32);
        src = qkv_w; dst = qwT; C = QKVN;
    } else {
        int j = id - CVT_BLK - TRQ_BLK;
        bx = j % (DIM/32); by = j / (DIM/32);
        src = proj_w; dst = pwT; C = DIM;
    }
    const int R = DIM;
    const int tx = t & 31, ty = t >> 5;
    for (int j = 0; j < 4; ++j)
        tile[ty + j*8][tx] = src[(size_t)(by*32 + ty + j*8) * C + bx*32 + tx];
    __syncthreads();
    for (int j = 0; j < 4; ++j)
        dst[(size_t)(bx*32 + ty + j*8) * R + by*32 + tx] = __float2bfloat16(tile[tx][ty + j*8]);
}

// ---------------- QKV GEMM: 256x192 tile, 6-phase counted-vmcnt (round-8 exact) ----------------
__global__ __launch_bounds__(512, 2) void gemm_qkv(
    const bf16* __restrict__ A, const bf16* __restrict__ B, const float* __restrict__ bias,
    bf16* __restrict__ outb, bf16* __restrict__ vTo)
{
    constexpr int K = DIM;           // 768: 12 K-tiles, 6 iters
    constexpr int N = QKVN;          // 2304
    constexpr int GX = N / 192;      // 12
    constexpr int NWG = GX * (MROWS / 256);  // 480
    constexpr int CHUNK = NWG / 8;   // 60

    __shared__ __align__(16) bf16 As[2][256*64];   // 64 KiB
    __shared__ __align__(16) bf16 Bs[2][192*64];   // 48 KiB

    const int t = threadIdx.x;
    const int lane = t & 63, wave = t >> 6;
    const int l15 = lane & 15, quad = lane >> 4;
    const int wm = wave >> 1;        // M quarter (0..3): rows wm*64
    const int wn = wave & 1;         // N half (0..1): cols wn*96

    int lin = blockIdx.x;
    lin = (lin & 7) * CHUNK + (lin >> 3);      // XCD-chunked bijection (480%8==0)
    const int m0 = (lin / GX) * 256, n0 = (lin % GX) * 192;

    floatx4 acc[4][6];
    floatx4 zero = {0.f, 0.f, 0.f, 0.f};
#pragma unroll
    for (int i = 0; i < 4; ++i)
#pragma unroll
        for (int j = 0; j < 6; ++j)
            acc[i][j] = zero;

    const int trow = t >> 3;
    const int gc = ((t & 7) ^ (trow & 7)) << 3;
    const bf16* Ag = A + (size_t)(m0 + trow) * K + gc;
    const bf16* Bg = B + (size_t)(n0 + trow) * K + gc;
    const int tb = t * 8;

#define STG_A(buf,s,tcol) async_ld16(Ag + (size_t)(s)*64*K + (tcol), &As[buf][(s)*4096 + tb])
#define STG_B(buf,s,tcol) async_ld16(Bg + (size_t)(s)*64*K + (tcol), &Bs[buf][(s)*4096 + tb])

    const int sw8 = (quad ^ (l15 & 7)) << 3;
    const int aoff = (wm*64 + l15) * 64 + sw8;    // + fm*1024
    const int boff = (wn*96 + l15) * 64 + sw8;    // + fn*1024

    short8 afr[4][2], bfr[2][2];

#define RD_A(buf) do { \
    _Pragma("unroll") \
    for (int f = 0; f < 4; ++f) { \
        afr[f][0] = *(const short8*)&As[buf][aoff + f*1024]; \
        afr[f][1] = *(const short8*)&As[buf][(aoff + f*1024) ^ 32]; \
    } } while (0)

#define RD_B2(buf, fp) do { \
    bfr[0][0] = *(const short8*)&Bs[buf][boff + (2*(fp))*1024]; \
    bfr[0][1] = *(const short8*)&Bs[buf][(boff + (2*(fp))*1024) ^ 32]; \
    bfr[1][0] = *(const short8*)&Bs[buf][boff + (2*(fp)+1)*1024]; \
    bfr[1][1] = *(const short8*)&Bs[buf][(boff + (2*(fp)+1)*1024) ^ 32]; \
    } while (0)

#define MFMA16(fp) do { \
    __builtin_amdgcn_s_setprio(1); \
    _Pragma("unroll") \
    for (int fm = 0; fm < 4; ++fm) { \
        acc[fm][2*(fp)]   = mfma16(bfr[0][0], afr[fm][0], acc[fm][2*(fp)]); \
        acc[fm][2*(fp)+1] = mfma16(bfr[1][0], afr[fm][0], acc[fm][2*(fp)+1]); \
    } \
    _Pragma("unroll") \
    for (int fm = 0; fm < 4; ++fm) { \
        acc[fm][2*(fp)]   = mfma16(bfr[0][1], afr[fm][1], acc[fm][2*(fp)]); \
        acc[fm][2*(fp)+1] = mfma16(bfr[1][1], afr[fm][1], acc[fm][2*(fp)+1]); \
    } \
    __builtin_amdgcn_s_setprio(0); \
} while (0)

#define BAR_LG0() do { \
    __builtin_amdgcn_s_barrier(); \
    asm volatile("s_waitcnt lgkmcnt(0)" ::: "memory"); \
    __builtin_amdgcn_sched_barrier(0); \
} while (0)

    STG_A(0,0,0); STG_A(0,1,0); STG_A(0,2,0); STG_A(0,3,0);
    STG_B(0,0,0); STG_B(0,1,0); STG_B(0,2,0);
    STG_A(1,0,64); STG_A(1,1,64); STG_A(1,2,64); STG_A(1,3,64);
    asm volatile("s_waitcnt vmcnt(4)" ::: "memory");
    __builtin_amdgcn_s_barrier();

    for (int it = 0; it < 6; ++it) {
        const int kb = it * 128;
        const bool more = (it < 5);
        RD_A(0); RD_B2(0, 0);
        STG_B(1,0,kb+64); STG_B(1,1,kb+64); STG_B(1,2,kb+64);
        asm volatile("s_waitcnt lgkmcnt(8)" ::: "memory");
        BAR_LG0();
        MFMA16(0);
        __builtin_amdgcn_sched_barrier(0);
        __builtin_amdgcn_s_barrier();
        RD_B2(0, 1);
        if (more) { STG_A(0,0,kb+128); STG_A(0,1,kb+128); STG_A(0,2,kb+128); STG_A(0,3,kb+128); }
        BAR_LG0();
        MFMA16(1);
        __builtin_amdgcn_sched_barrier(0);
        __builtin_amdgcn_s_barrier();
        RD_B2(0, 2);
        BAR_LG0();
        MFMA16(2);
        __builtin_amdgcn_sched_barrier(0);
        if (more) { asm volatile("s_waitcnt vmcnt(4)" ::: "memory"); }
        else      { asm volatile("s_waitcnt vmcnt(0)" ::: "memory"); }
        __builtin_amdgcn_s_barrier();
        RD_A(1); RD_B2(1, 0);
        if (more) { STG_B(0,0,kb+128); STG_B(0,1,kb+128); STG_B(0,2,kb+128); }
        asm volatile("s_waitcnt lgkmcnt(8)" ::: "memory");
        BAR_LG0();
        MFMA16(0);
        __builtin_amdgcn_sched_barrier(0);
        __builtin_amdgcn_s_barrier();
        RD_B2(1, 1);
        if (more) { STG_A(1,0,kb+192); STG_A(1,1,kb+192); STG_A(1,2,kb+192); STG_A(1,3,kb+192); }
        BAR_LG0();
        MFMA16(1);
        __builtin_amdgcn_sched_barrier(0);
        __builtin_amdgcn_s_barrier();
        RD_B2(1, 2);
        BAR_LG0();
        MFMA16(2);
        __builtin_amdgcn_sched_barrier(0);
        if (more) { asm volatile("s_waitcnt vmcnt(4)" ::: "memory"); }
        __builtin_amdgcn_s_barrier();
    }
#undef RD_A
#undef RD_B2
#undef MFMA16
#undef BAR_LG0
#undef STG_A
#undef STG_B

    const int mb = m0 + wm * 64;
    const int nb = n0 + wn * 96;

    if (n0 >= 2*DIM) {
        bf16* S = &As[0][0] + wave * 2048;
        unsigned short* Su = (unsigned short*)S;
        const int batch = mb / NN;
        const int tokb = mb % NN;
        const int dl = lane >> 2, cc = (lane & 3) * 16;
#pragma unroll
        for (int fn = 0; fn < 6; ++fn) {
            int cb = nb + fn*16;
            int bh = batch * NH + ((cb - 2*DIM) >> 6);
            int dbase = cb & 63;
            float4 bv = *(const float4*)(bias + cb + quad*4);
            float bvr[4] = {bv.x, bv.y, bv.z, bv.w};
#pragma unroll
            for (int fm = 0; fm < 4; ++fm) {
#pragma unroll
                for (int r = 0; r < 4; ++r) {
                    float v = acc[fm][fn][r] + bvr[r];
                    Su[(quad*4 + r)*72 + fm*16 + l15] =
                        (unsigned short)(__float_as_uint(v) >> 16);
                }
            }
            uint4 r0 = *(const uint4*)(S + dl*72 + cc);
            uint4 r1 = *(const uint4*)(S + dl*72 + cc + 8);
            bf16* dst = vTo + ((size_t)bh * HD + dbase + dl) * NN + tokb + cc;
            *(uint4*)dst = r0;
            *(uint4*)(dst + 8) = r1;
        }
        return;
    }

#pragma unroll
    for (int fm = 0; fm < 4; ++fm) {
        int m = mb + fm*16 + l15;
        bf16* row = outb + (size_t)m * N;
#pragma unroll
        for (int fn = 0; fn < 6; ++fn) {
            int n = nb + fn*16 + quad*4;
            float4 bv = *(const float4*)(bias + n);
            float v0 = acc[fm][fn][0] + bv.x;
            float v1 = acc[fm][fn][1] + bv.y;
            float v2 = acc[fm][fn][2] + bv.z;
            float v3 = acc[fm][fn][3] + bv.w;
            if (n < DIM) { v0 *= QSCALE; v1 *= QSCALE; v2 *= QSCALE; v3 *= QSCALE; }
            *(uint2*)(row + n) = make_uint2(pack_rne(v0, v1), pack_rne(v2, v3));
        }
    }
}

// ---------------- proj GEMM: C = A @ B^T (128x128, round-8 exact) ----------------
template<int MODE>
__global__ __launch_bounds__(256) void gemm_bt(
    const bf16* __restrict__ A, const bf16* __restrict__ B, const float* __restrict__ bias,
    int M, int N, int K,
    bf16* __restrict__ outb, bf16* __restrict__ vTo, float* __restrict__ outf)
{
    __shared__ __align__(16) bf16 As[2][128*64];
    __shared__ __align__(16) bf16 Bs[2][128*64];

    const int t = threadIdx.x;
    const int lane = t & 63, wave = t >> 6;
    const int l15 = lane & 15, quad = lane >> 4;
    const int wm = (wave >> 1) * 64, wn = (wave & 1) * 64;

    constexpr int GX  = (MODE == 0) ? (QKVN/128) : (DIM/128);
    constexpr int NWG = GX * (MROWS/128);
    constexpr int CHUNK = NWG / 8;
    int lin = blockIdx.y * GX + blockIdx.x;
    lin = (lin & 7) * CHUNK + (lin >> 3);
    const int m0 = (lin / GX) * 128, n0 = (lin % GX) * 128;

    floatx4 acc[4][4];
    floatx4 zero = {0.f, 0.f, 0.f, 0.f};
    for (int i = 0; i < 4; ++i)
        for (int j = 0; j < 4; ++j)
            acc[i][j] = zero;

    const int trow = t >> 3;
    const int gc = ((t & 7) ^ (trow & 7)) << 3;
    const bf16* aA = A + (size_t)(m0 + trow) * K + gc;
    const bf16* aB = B + (size_t)(n0 + trow) * K + gc;
    const int lb = wave * 512;

    for (int s = 0; s < 4; ++s) {
        async_ld16(aA + (size_t)s*32*K, &As[0][s*2048 + lb]);
        async_ld16(aB + (size_t)s*32*K, &Bs[0][s*2048 + lb]);
    }

    const int sw = l15 & 7;
    const int nit = K >> 6;
    for (int kt = 0; kt < nit; ++kt) {
        const int cur = kt & 1;
        __syncthreads();
        if (kt + 1 < nit) {
            const bf16* pA = aA + (size_t)(kt+1)*64;
            const bf16* pB = aB + (size_t)(kt+1)*64;
            for (int s = 0; s < 4; ++s) {
                async_ld16(pA + (size_t)s*32*K, &As[cur^1][s*2048 + lb]);
                async_ld16(pB + (size_t)s*32*K, &Bs[cur^1][s*2048 + lb]);
            }
        }
        short8 af0[4], af1[4], bf0[4], bf1[4];
        for (int fm = 0; fm < 4; ++fm) {
            int base = (wm + fm*16 + l15) * 64 + ((quad ^ sw) << 3);
            af0[fm] = *(const short8*)(&As[cur][base]);
            af1[fm] = *(const short8*)(&As[cur][base ^ 32]);
        }
        for (int fn = 0; fn < 4; ++fn) {
            int base = (wn + fn*16 + l15) * 64 + ((quad ^ sw) << 3);
            bf0[fn] = *(const short8*)(&Bs[cur][base]);
            bf1[fn] = *(const short8*)(&Bs[cur][base ^ 32]);
        }
        for (int fm = 0; fm < 4; ++fm)
            for (int fn = 0; fn < 4; ++fn) {
                acc[fm][fn] = mfma16(bf0[fn], af0[fm], acc[fm][fn]);
                acc[fm][fn] = mfma16(bf1[fn], af1[fm], acc[fm][fn]);
            }
    }

    for (int fm = 0; fm < 4; ++fm) {
        int m = m0 + wm + fm*16 + l15;
        float* row = outf + (size_t)m * N;
        for (int fn = 0; fn < 4; ++fn) {
            int n = n0 + wn + fn*16 + quad*4;
            float4 bv = *(const float4*)(bias + n);
            float4 v;
            v.x = acc[fm][fn][0] + bv.x;
            v.y = acc[fm][fn][1] + bv.y;
            v.z = acc[fm][fn][2] + bv.z;
            v.w = acc[fm][fn][3] + bv.w;
            *(float4*)(row + n) = v;
        }
    }
}

// ---------------- fused attention v9: v7 body, 8-wave blocks (round-8 exact) ----------------
__global__ __launch_bounds__(512) void attn_kernel(
    const bf16* __restrict__ qkv, const bf16* __restrict__ vT,
    const float* __restrict__ w2, bf16* __restrict__ ao)
{
    int lin = blockIdx.y * BH + blockIdx.x;     // grid (192, 5)
    int j = lin >> 3;
    const int bh = (lin & 7) + 8 * (j / 5);     // bijective: 8 * 24 * 5 = 960
    const int qt = j % 5;
    const int b = bh / NH, h = bh - b * NH;
    const int t = threadIdx.x;
    const int wave = t >> 6, lane = t & 63;
    const int l15 = lane & 15, quad = lane >> 4;
    const int qrow0 = qt * 128 + wave * 16;

    float w0 = w2[0], w1 = w2[1];
    float wmx = fmaxf(w0, w1);
    float e0 = __expf(w0 - wmx), e1 = __expf(w1 - wmx);
    float ws0 = e0 / (e0 + e1);
    float ws1 = (1.0f - ws0) * LN2SQ;

    __shared__ __align__(16) bf16 Kb[2][64*64];
    __shared__ __align__(16) bf16 Vb[2][64*64];
    __shared__ __align__(16) bf16 Ps[8][16*72];
    __shared__ __align__(16) bf16 Pr[8][16*72];

    const bf16* kb = qkv + (size_t)(b*NN)*QKVN + DIM + h*HD;
    const bf16* vb = vT + (size_t)bh * HD * NN;

    const bf16* qr = qkv + (size_t)(b*NN + qrow0 + l15) * QKVN + h*HD;
    short8 aq0 = *(const short8*)(qr + quad*8);
    short8 aq1 = *(const short8*)(qr + 32 + quad*8);

    const int srow = t >> 3;
    const int gc   = ((t & 7) ^ (srow & 7)) << 3;
    const bf16* kst = kb + (size_t)srow * QKVN + gc;
    const bf16* vst = vb + (size_t)srow * NN + gc;
    const int lb = t * 8;

    async_ld16(kst, &Kb[0][lb]);
    async_ld16(vst, &Vb[0][lb]);

    floatx4 zero = {0.f, 0.f, 0.f, 0.f};
    floatx4 accS[4], accR[4];
    for (int i = 0; i < 4; ++i) { accS[i] = zero; accR[i] = zero; }
    float lsum = 0.f;

    const int sw = l15 & 7;
    const int fbase = l15 * 64 + ((quad ^ sw) << 3);

    unsigned* PsW = (unsigned*)&Ps[wave][0];
    unsigned* PrW = (unsigned*)&Pr[wave][0];
    const int wb = l15*36 + quad*2;
    const bf16* PsR = &Ps[wave][l15*72 + quad*8];
    const bf16* PrR = &Pr[wave][l15*72 + quad*8];

#pragma unroll 2
    for (int kt = 0; kt < 10; ++kt) {
        const int cur = kt & 1;
        __syncthreads();
        if (kt + 1 < 10) {
            kst += (size_t)64 * QKVN;
            vst += 64;
            async_ld16(kst, &Kb[cur^1][lb]);
            async_ld16(vst, &Vb[cur^1][lb]);
        }

        const bf16* Kc = &Kb[cur][0];
        const bf16* Vc = &Vb[cur][0];

        floatx4 s[4];
        for (int I = 0; I < 4; ++I) {
            short8 aklo = *(const short8*)(Kc + fbase + I*1024);
            short8 akhi = *(const short8*)(Kc + ((fbase + I*1024) ^ 32));
            s[I] = zero;
            s[I] = mfma16(aklo, aq0, s[I]);
            s[I] = mfma16(akhi, aq1, s[I]);
        }

        short8 bvlo[4], bvhi[4];
        for (int dt = 0; dt < 4; ++dt) {
            bvlo[dt] = *(const short8*)(Vc + fbase + dt*1024);
            bvhi[dt] = *(const short8*)(Vc + ((fbase + dt*1024) ^ 32));
        }

        for (int I = 0; I < 4; ++I) {
            float ex[4], rq[4];
            for (int r = 0; r < 4; ++r) {
                ex[r] = fexp2(s[I][r]);
                float m = fmaxf(s[I][r], 0.f);
                rq[r] = m * m;
                lsum += ex[r];
            }
            *(uint2*)(PsW + wb + I*8) = make_uint2(pack_trunc(ex[0],ex[1]), pack_trunc(ex[2],ex[3]));
            *(uint2*)(PrW + wb + I*8) = make_uint2(pack_trunc(rq[0],rq[1]), pack_trunc(rq[2],rq[3]));
        }

        short8 paSlo = *(const short8*)PsR;
        short8 paShi = *(const short8*)(PsR + 32);
        short8 paRlo = *(const short8*)PrR;
        short8 paRhi = *(const short8*)(PrR + 32);

        for (int dt = 0; dt < 4; ++dt) {
            accS[dt] = mfma16(paSlo, bvlo[dt], accS[dt]);
            accS[dt] = mfma16(paShi, bvhi[dt], accS[dt]);
            accR[dt] = mfma16(paRlo, bvlo[dt], accR[dt]);
            accR[dt] = mfma16(paRhi, bvhi[dt], accR[dt]);
        }
    }

    lsum += __shfl_xor(lsum, 16);
    lsum += __shfl_xor(lsum, 32);
    float invq[4];
    for (int r = 0; r < 4; ++r)
        invq[r] = 1.0f / __shfl(lsum, quad*4 + r);

    for (int dt = 0; dt < 4; ++dt) {
        for (int r = 0; r < 4; ++r) {
            float v = ws0 * accS[dt][r] * invq[r] + ws1 * accR[dt][r];
            int tok = qrow0 + quad*4 + r;
            ao[((size_t)(b * NN + tok)) * DIM + h * HD + dt*16 + l15] = __float2bfloat16(v);
        }
    }
}

// ---------------- launch ----------------

extern "C" void kernel_launch(void* const* d_in, const int* in_sizes, int n_in,
                              void* d_out, int out_size, void* d_ws, size_t ws_size,
                              hipStream_t stream) {
    const float* x      = (const float*)d_in[0];
    const float* qkv_w  = (const float*)d_in[1];
    const float* qkv_b  = (const float*)d_in[2];
    const float* proj_w = (const float*)d_in[3];
    const float* proj_b = (const float*)d_in[4];
    const float* w2     = (const float*)d_in[5];
    float* out = (float*)d_out;

    bf16* xb   = (bf16*)d_ws;                       // 10240*768   (reused as ao later)
    bf16* qwT  = xb   + (size_t)MROWS * DIM;        // 2304*768
    bf16* pwT  = qwT  + (size_t)QKVN * DIM;         // 768*768
    bf16* qkvb = pwT  + (size_t)DIM * DIM;          // 10240*2304 (V cols unused)
    bf16* vT   = qkvb + (size_t)MROWS * QKVN;       // 192*64*640
    bf16* ao   = xb;                                 // alias: xb dead after qkv gemm

    prep_all<<<CVT_BLK + TRQ_BLK + TRP_BLK, 256, 0, stream>>>(
        x, qkv_w, proj_w, xb, qwT, pwT);

    gemm_qkv<<<dim3((QKVN/192) * (MROWS/256)), 512, 0, stream>>>(
        xb, qwT, qkv_b, qkvb, vT);

    attn_kernel<<<dim3(BH, NN / 128), 512, 0, stream>>>(qkvb, vT, w2, ao);

    gemm_bt<1><<<dim3(DIM / 128, MROWS / 128), 256, 0, stream>>>(
        ao, pwT, proj_b, MROWS, DIM, DIM, nullptr, nullptr, out);
}